// Round 9
// baseline (290.162 us; speedup 1.0000x reference)
//
#include <hip/hip_runtime.h>
#include <hip/hip_bf16.h>
#include <math.h>

// ---------- types ----------
typedef __bf16 bf16x8 __attribute__((ext_vector_type(8)));
typedef float  f32x4  __attribute__((ext_vector_type(4)));

#define B_ROWS 8192
#define HSZ    1024

// async global->LDS, 16B per lane. LDS dest must be wave-uniform-base + lane*16.
#define GLOAD16(gsrc, ldst)                                                          \
  __builtin_amdgcn_global_load_lds((const __attribute__((address_space(1))) void*)(gsrc), \
                                   (__attribute__((address_space(3))) void*)(ldst),  \
                                   16, 0, 0)

__device__ inline unsigned short f2bf(float f) {
  union { float f; unsigned u; } x; x.f = f;
  unsigned r = x.u + 0x7fffu + ((x.u >> 16) & 1u);   // RNE
  return (unsigned short)(r >> 16);
}

__device__ inline void store4bf(unsigned short* p, float4 v) {
  ushort4 u;
  u.x = f2bf(v.x); u.y = f2bf(v.y); u.z = f2bf(v.z); u.w = f2bf(v.w);
  *(ushort4*)p = u;  // 8B store
}

__device__ inline float sigm(float x) { return 1.0f / (1.0f + __expf(-x)); }

// ---------- kernel 0: fp32 -> bf16 conversion + T precompute ----------
__global__ void k_convert(const float* __restrict__ inp,   // [8192][1025]
                          const float* __restrict__ h,     // [8192][1024]
                          const float* __restrict__ Wl,    // [4096][2048]
                          const float* __restrict__ Wd,    // [1024][1024]
                          unsigned short* __restrict__ comb, // [8192][2048] bf16 bits (cols 0..1023 = x)
                          unsigned short* __restrict__ Wlb,  // [4096][2048]
                          unsigned short* __restrict__ hb,   // [8192][1024]
                          unsigned short* __restrict__ Wdb,  // [1024][1024]
                          float* __restrict__ Tm1) {         // [8192] = T-1
  const long stride = (long)gridDim.x * blockDim.x;
  const long tid0 = (long)blockIdx.x * blockDim.x + threadIdx.x;

  for (long i = tid0; i < (long)B_ROWS * HSZ / 4; i += stride) {
    float4 v = ((const float4*)h)[i];
    store4bf(hb + i * 4, v);
  }
  for (long i = tid0; i < (long)B_ROWS * HSZ / 4; i += stride) {
    long e = i * 4; long b = e >> 10; long c = e & 1023;
    float4 v = *(const float4*)(inp + b * 1025 + c);
    store4bf(comb + b * 2048 + c, v);
  }
  for (long i = tid0; i < 4096L * 2048 / 4; i += stride) {
    float4 v = ((const float4*)Wl)[i];
    store4bf(Wlb + i * 4, v);
  }
  for (long i = tid0; i < 1024L * 1024 / 4; i += stride) {
    float4 v = ((const float4*)Wd)[i];
    store4bf(Wdb + i * 4, v);
  }
  for (long i = tid0; i < B_ROWS; i += stride) {
    float dt = inp[i * 1025 + 1024];
    Tm1[i] = 1.0f / logf(dt + 2.7183f) - 1.0f;
  }
}

// ---------- kernel 1: C_ST GEMM (8192x1024x1024) + h_adj epilogue (known-good) ----------
__global__ void k_gemm1(const unsigned short* __restrict__ A,   // hb  [8192][1024]
                        const unsigned short* __restrict__ Bm,  // Wdb [1024][1024]
                        const float* __restrict__ h,            // h_cur f32
                        const float* __restrict__ bd,           // b_desc [1024]
                        const float* __restrict__ Tm1,
                        unsigned short* __restrict__ comb) {
  const int K = 1024;
  __shared__ __align__(16) unsigned short As[128 * 32];
  __shared__ __align__(16) unsigned short Bs[128 * 32];
  const int tid = threadIdx.x;
  const int lane = tid & 63;
  const int wave = tid >> 6;
  const int wr = wave >> 1, wc = wave & 1;
  const int bRow = blockIdx.x;    // 0..63
  const int bCol = blockIdx.y;    // 0..7

  const int sRow = tid >> 2;
  const int sK = (tid & 3) * 8;
  const unsigned short* aSrc0 = A + (long)(bRow * 128 + sRow) * K + sK;
  const unsigned short* aSrc1 = A + (long)(bRow * 128 + 64 + sRow) * K + sK;
  const unsigned short* bSrc0 = Bm + (long)(bCol * 128 + sRow) * K + sK;
  const unsigned short* bSrc1 = Bm + (long)(bCol * 128 + 64 + sRow) * K + sK;
  unsigned short* aDst0 = As + tid * 8;
  unsigned short* aDst1 = As + 2048 + tid * 8;
  unsigned short* bDst0 = Bs + tid * 8;
  unsigned short* bDst1 = Bs + 2048 + tid * 8;

  f32x4 acc[4][4] = {};
  const int fr = lane & 15, fk = (lane >> 4) * 8;

  for (int k0 = 0; k0 < K; k0 += 32) {
    GLOAD16(aSrc0 + k0, aDst0);
    GLOAD16(aSrc1 + k0, aDst1);
    GLOAD16(bSrc0 + k0, bDst0);
    GLOAD16(bSrc1 + k0, bDst1);
    __syncthreads();
    bf16x8 a[4], b[4];
#pragma unroll
    for (int m = 0; m < 4; m++) a[m] = *(const bf16x8*)(As + (wr * 64 + m * 16 + fr) * 32 + fk);
#pragma unroll
    for (int n = 0; n < 4; n++) b[n] = *(const bf16x8*)(Bs + (wc * 64 + n * 16 + fr) * 32 + fk);
#pragma unroll
    for (int m = 0; m < 4; m++)
#pragma unroll
      for (int n = 0; n < 4; n++)
        acc[m][n] = __builtin_amdgcn_mfma_f32_16x16x32_bf16(a[m], b[n], acc[m][n], 0, 0, 0);
    __syncthreads();
  }

  const int cr = (lane >> 4) * 4;
  const int cc = lane & 15;
#pragma unroll
  for (int m = 0; m < 4; m++)
#pragma unroll
    for (int n = 0; n < 4; n++) {
      const int col = bCol * 128 + wc * 64 + n * 16 + cc;
#pragma unroll
      for (int r = 0; r < 4; r++) {
        const int row = bRow * 128 + wr * 64 + m * 16 + cr + r;
        float v = acc[m][n][r] + bd[col];
        float cst = tanhf(v);
        float hadj = h[(long)row * HSZ + col] + Tm1[row] * cst;
        comb[(long)row * 2048 + 1024 + col] = f2bf(hadj);
      }
    }
}

// ---------- kernel 2: gates GEMM, 256x256, ring-4 LDS, MINIMAL-FENCE schedule ----------
// R9 change: remove ALL sched_barrier(0) and manual lgkmcnt (compiler auto-schedules
// ds_read->MFMA with fine-grained lgkmcnt — m97/m141 evidence). One "memory"-fenced
// counted vmcnt per tile at the publish point; bare s_barrier elsewhere.
// Ledger: per tile P1 issues A(t+3)[2], P2 issues B(t+3)[2]. Before VMW in P1 of t:
// outstanding = {A(t+2),B(t+2),A(t+3)} = 6 -> vmcnt(6) = no-wait, guarantees <=B(t+1)
// landed -> tile t+1 published before P2 reads it. Tail: VMW(0) at t==NT2-2.
#define NT2 64   // 2048/32
__global__ __launch_bounds__(512, 2)
void k_gemm2_mf(const unsigned short* __restrict__ A,   // comb [8192][2048]
                const unsigned short* __restrict__ Bm,  // Wlb  [4096][2048]
                const float* __restrict__ bl,           // b_layers [4096]
                const float* __restrict__ c_cur,        // f32 [8192][1024]
                float* __restrict__ out) {              // h_next | c_next (f32)
  __shared__ __align__(16) unsigned short lds[4][16384];

  const int tid = threadIdx.x;
  const int lane = tid & 63;
  const int wid = tid >> 6;
  const int wr = wid >> 2;          // 0..1 : row half (128 rows)
  const int wc = wid & 3;           // 0..3 : col quarter (16 j x 4 gates)

  // L2-aware XCD mapping (R6, best measured FETCH)
  const int bid = blockIdx.x;
  const int xcd = bid & 7;
  const int ii = bid >> 3;
  const int sweep = ii >> 5;
  const int pos = ii & 31;
  const int bRow = xcd * 4 + sweep * 2 + (pos & 1);   // 0..31
  const int bCol = pos >> 1;                          // 0..15

  // ---- staging addresses (pre-swizzled global source; LDS dest linear) ----
  const int sr = tid >> 2;                 // 0..127
  const int swsel = (sr >> 1) & 3;
  const int gk = ((tid & 3) ^ swsel) << 3;
  const unsigned short* aBase = A + (long)(bRow * 256 + sr) * 2048 + gk;
  const int rl0 = sr, rl1 = 128 + sr;
  const int grow0 = ((rl0 >> 4) & 3) * 1024 + bCol * 64 + (rl0 >> 6) * 16 + (rl0 & 15);
  const int grow1 = ((rl1 >> 4) & 3) * 1024 + bCol * 64 + (rl1 >> 6) * 16 + (rl1 & 15);
  const unsigned short* bBase0 = Bm + (long)grow0 * 2048 + gk;
  const unsigned short* bBase1 = Bm + (long)grow1 * 2048 + gk;

#define STAGE_A2(tt) { unsigned short* d_ = &lds[(tt) & 3][0] + tid * 8;          \
    GLOAD16(aBase + (long)(tt) * 32, d_);                                          \
    GLOAD16(aBase + 128L * 2048 + (long)(tt) * 32, d_ + 512 * 8); }
#define STAGE_B2(tt) { unsigned short* d_ = &lds[(tt) & 3][8192] + tid * 8;       \
    GLOAD16(bBase0 + (long)(tt) * 32, d_);                                         \
    GLOAD16(bBase1 + (long)(tt) * 32, d_ + 512 * 8); }

  // ---- fragment read offsets (swizzled), in ushort units ----
  const int fr = lane & 15, q = lane >> 4;
  int offA[8], offB[4];
#pragma unroll
  for (int m = 0; m < 8; m++) {
    const int row = wr * 128 + m * 16 + fr;
    offA[m] = row * 32 + ((q ^ ((row >> 1) & 3)) << 3);
  }
#pragma unroll
  for (int n = 0; n < 4; n++) {
    const int row = wc * 64 + n * 16 + fr;
    offB[n] = 8192 + row * 32 + ((q ^ ((row >> 1) & 3)) << 3);
  }

  f32x4 acc[8][4] = {};   // [m][gate]
  bf16x8 aL0[4], aL1[4], b0[4], b1[4], aH[4];

  // ---- prologue: stage tiles 0,1,2; publish tile 0; read tile-0 phase-A frags ----
  STAGE_A2(0); STAGE_B2(0);
  STAGE_A2(1); STAGE_B2(1);
  STAGE_A2(2); STAGE_B2(2);
  asm volatile("s_waitcnt vmcnt(8)" ::: "memory");   // oldest 4 = tile 0 A+B landed
  __builtin_amdgcn_s_barrier();
#pragma unroll
  for (int m = 0; m < 4; m++) aL0[m] = *(const bf16x8*)(&lds[0][0] + offA[m]);
#pragma unroll
  for (int n = 0; n < 4; n++) b0[n] = *(const bf16x8*)(&lds[0][0] + offB[n]);

  // TILE_BODY(t, aC, bC, aN, bN): minimal-fence two-phase tile.
#define TILE_BODY(t, aC, bC, aN, bN)                                                 \
  {                                                                                  \
    const unsigned short* buf = lds[(t) & 3];                                        \
    /* P1: aH reads + stage A(t+3); MFMA m0-3 on (aC,bC) */                          \
    _Pragma("unroll")                                                                \
    for (int m = 0; m < 4; m++) aH[m] = *(const bf16x8*)(buf + offA[m + 4]);         \
    if ((t) < NT2 - 3) STAGE_A2((t) + 3);                                            \
    __builtin_amdgcn_s_setprio(1);                                                   \
    _Pragma("unroll")                                                                \
    for (int m = 0; m < 4; m++)                                                      \
      _Pragma("unroll")                                                              \
      for (int n = 0; n < 4; n++)                                                    \
        acc[m][n] = __builtin_amdgcn_mfma_f32_16x16x32_bf16(aC[m], bC[n], acc[m][n], 0, 0, 0); \
    __builtin_amdgcn_s_setprio(0);                                                   \
    /* publish point: the ONLY compiler memory fence in the tile */                  \
    if ((t) == NT2 - 2) { asm volatile("s_waitcnt vmcnt(0)" ::: "memory"); }         \
    else                { asm volatile("s_waitcnt vmcnt(6)" ::: "memory"); }         \
    __builtin_amdgcn_s_barrier();                                                    \
    /* P2: next-tile reads + stage B(t+3); MFMA m4-7 on (aH,bC) */                   \
    if ((t) < NT2 - 1) {                                                             \
      const unsigned short* bufN = lds[((t) + 1) & 3];                               \
      _Pragma("unroll")                                                              \
      for (int m = 0; m < 4; m++) aN[m] = *(const bf16x8*)(bufN + offA[m]);          \
      _Pragma("unroll")                                                              \
      for (int n = 0; n < 4; n++) bN[n] = *(const bf16x8*)(bufN + offB[n]);          \
      if ((t) < NT2 - 3) STAGE_B2((t) + 3);                                          \
    }                                                                                \
    __builtin_amdgcn_s_setprio(1);                                                   \
    _Pragma("unroll")                                                                \
    for (int m = 0; m < 4; m++)                                                      \
      _Pragma("unroll")                                                              \
      for (int n = 0; n < 4; n++)                                                    \
        acc[m + 4][n] = __builtin_amdgcn_mfma_f32_16x16x32_bf16(aH[m], bC[n], acc[m + 4][n], 0, 0, 0); \
    __builtin_amdgcn_s_setprio(0);                                                   \
    __builtin_amdgcn_s_barrier();                                                    \
  }

  for (int t = 0; t < NT2; t += 2) {
    TILE_BODY(t,     aL0, b0, aL1, b1);
    TILE_BODY(t + 1, aL1, b1, aL0, b0);
  }
#undef TILE_BODY

  // ---- fused LSTM epilogue ----
  const int cr = (lane >> 4) * 4;
  const int cc = lane & 15;
  const int j = bCol * 64 + wc * 16 + cc;       // 0..1023
#pragma unroll
  for (int m = 0; m < 8; m++) {
#pragma unroll
    for (int r = 0; r < 4; r++) {
      const int row = bRow * 256 + wr * 128 + m * 16 + cr + r;
      float iv = sigm(acc[m][0][r] + bl[j]);
      float fv = sigm(acc[m][1][r] + bl[1024 + j]);
      float ov = sigm(acc[m][2][r] + bl[2048 + j]);
      float gv = tanhf(acc[m][3][r] + bl[3072 + j]);
      float cn = fv * c_cur[(long)row * HSZ + j] + iv * gv;
      float hn = ov * tanhf(cn);
      out[(long)row * HSZ + j] = hn;                         // h_next
      out[(long)B_ROWS * HSZ + (long)row * HSZ + j] = cn;    // c_next
    }
  }
}

// ---------- diagnostic: MFMA + barriers only (no loads/stores in loop) ----------
// Same 8-wave / 128KB-LDS / 2-barrier-per-tile skeleton, 128 K32-equivalent tiles.
// Splits the residual: ~82us => MFMA+sync floor OK (cost is load-side);
// ~180us => 2-wave/SIMD barrier-lockstep is the wall.
__global__ __launch_bounds__(512, 2)
void k_diag(float* __restrict__ wsout) {
  __shared__ __align__(16) unsigned short lds[4][16384];
  const int tid = threadIdx.x;
  const int lane = tid & 63;
  for (int i = tid; i < 4 * 16384 / 4; i += 512)
    ((unsigned long long*)lds)[i] = (unsigned long long)(i * 2654435761u);
  __syncthreads();
  bf16x8 aC[4], aH[4], bC[4];
  const unsigned short* buf = &lds[0][0];
#pragma unroll
  for (int m = 0; m < 4; m++) {
    aC[m] = *(const bf16x8*)(buf + lane * 8 + m * 512);
    aH[m] = *(const bf16x8*)(buf + 2048 + lane * 8 + m * 512);
    bC[m] = *(const bf16x8*)(buf + 4096 + lane * 8 + m * 512);
  }
  f32x4 acc[8][4] = {};
  for (int t = 0; t < 128; ++t) {
    __builtin_amdgcn_s_setprio(1);
#pragma unroll
    for (int m = 0; m < 4; m++)
#pragma unroll
      for (int n = 0; n < 4; n++)
        acc[m][n] = __builtin_amdgcn_mfma_f32_16x16x32_bf16(aC[m], bC[n], acc[m][n], 0, 0, 0);
    __builtin_amdgcn_s_setprio(0);
    __builtin_amdgcn_s_barrier();
    __builtin_amdgcn_s_setprio(1);
#pragma unroll
    for (int m = 0; m < 4; m++)
#pragma unroll
      for (int n = 0; n < 4; n++)
        acc[m + 4][n] = __builtin_amdgcn_mfma_f32_16x16x32_bf16(aH[m], bC[n], acc[m + 4][n], 0, 0, 0);
    __builtin_amdgcn_s_setprio(0);
    __builtin_amdgcn_s_barrier();
  }
  float s = 0.0f;
#pragma unroll
  for (int m = 0; m < 8; m++)
#pragma unroll
    for (int n = 0; n < 4; n++)
      s += acc[m][n][0] + acc[m][n][1] + acc[m][n][2] + acc[m][n][3];
  wsout[(long)blockIdx.x * 512 + tid] = s;   // dead ws region (hb, already consumed)
}

// ---------- launch ----------
extern "C" void kernel_launch(void* const* d_in, const int* in_sizes, int n_in,
                              void* d_out, int out_size, void* d_ws, size_t ws_size,
                              hipStream_t stream) {
  const float* inp = (const float*)d_in[0];   // input_tensor [8192][1025]
  const float* h   = (const float*)d_in[1];   // h_cur
  const float* c   = (const float*)d_in[2];   // c_cur
  const float* Wl  = (const float*)d_in[3];   // W_layers [4096][2048]
  const float* bl  = (const float*)d_in[4];   // b_layers [4096]
  const float* Wd  = (const float*)d_in[5];   // W_desc [1024][1024]
  const float* bd  = (const float*)d_in[6];   // b_desc [1024]

  char* ws = (char*)d_ws;
  unsigned short* comb = (unsigned short*)(ws);               // 33,554,432 B
  unsigned short* Wlb  = (unsigned short*)(ws + 33554432);    // 16,777,216 B
  unsigned short* hb   = (unsigned short*)(ws + 50331648);    // 16,777,216 B
  unsigned short* Wdb  = (unsigned short*)(ws + 67108864);    //  2,097,152 B
  float*          Tm1  = (float*)(ws + 69206016);             //     32,768 B
  float*          out  = (float*)d_out;                       // f32 outputs

  hipLaunchKernelGGL(k_convert, dim3(2048), dim3(256), 0, stream,
                     inp, h, Wl, Wd, comb, Wlb, hb, Wdb, Tm1);
  hipLaunchKernelGGL(k_gemm1, dim3(64, 8), dim3(256), 0, stream,
                     hb, Wdb, h, bd, Tm1, comb);
  hipLaunchKernelGGL(k_gemm2_mf, dim3(512), dim3(512), 0, stream,
                     comb, Wlb, bl, c, out);
  // diagnostic (writes only to dead hb region; rewritten by k_convert next call)
  hipLaunchKernelGGL(k_diag, dim3(256), dim3(512), 0, stream, (float*)hb);
}

// Round 10
// 237.925 us; speedup vs baseline: 1.2196x; 1.2196x over previous
//
#include <hip/hip_runtime.h>
#include <hip/hip_bf16.h>
#include <math.h>

// ---------- types ----------
typedef __bf16 bf16x8 __attribute__((ext_vector_type(8)));
typedef float  f32x4  __attribute__((ext_vector_type(4)));

#define B_ROWS 8192
#define HSZ    1024

// async global->LDS, 16B per lane. LDS dest must be wave-uniform-base + lane*16.
#define GLOAD16(gsrc, ldst)                                                          \
  __builtin_amdgcn_global_load_lds((const __attribute__((address_space(1))) void*)(gsrc), \
                                   (__attribute__((address_space(3))) void*)(ldst),  \
                                   16, 0, 0)

__device__ inline unsigned short f2bf(float f) {
  union { float f; unsigned u; } x; x.f = f;
  unsigned r = x.u + 0x7fffu + ((x.u >> 16) & 1u);   // RNE
  return (unsigned short)(r >> 16);
}

__device__ inline void store4bf(unsigned short* p, float4 v) {
  ushort4 u;
  u.x = f2bf(v.x); u.y = f2bf(v.y); u.z = f2bf(v.z); u.w = f2bf(v.w);
  *(ushort4*)p = u;  // 8B store
}

__device__ inline float sigm(float x) { return 1.0f / (1.0f + __expf(-x)); }

// ---------- kernel 0: fp32 -> bf16 conversion + T precompute ----------
__global__ void k_convert(const float* __restrict__ inp,   // [8192][1025]
                          const float* __restrict__ h,     // [8192][1024]
                          const float* __restrict__ Wl,    // [4096][2048]
                          const float* __restrict__ Wd,    // [1024][1024]
                          unsigned short* __restrict__ comb, // [8192][2048] bf16 bits (cols 0..1023 = x)
                          unsigned short* __restrict__ Wlb,  // [4096][2048]
                          unsigned short* __restrict__ hb,   // [8192][1024]
                          unsigned short* __restrict__ Wdb,  // [1024][1024]
                          float* __restrict__ Tm1) {         // [8192] = T-1
  const long stride = (long)gridDim.x * blockDim.x;
  const long tid0 = (long)blockIdx.x * blockDim.x + threadIdx.x;

  for (long i = tid0; i < (long)B_ROWS * HSZ / 4; i += stride) {
    float4 v = ((const float4*)h)[i];
    store4bf(hb + i * 4, v);
  }
  for (long i = tid0; i < (long)B_ROWS * HSZ / 4; i += stride) {
    long e = i * 4; long b = e >> 10; long c = e & 1023;
    float4 v = *(const float4*)(inp + b * 1025 + c);
    store4bf(comb + b * 2048 + c, v);
  }
  for (long i = tid0; i < 4096L * 2048 / 4; i += stride) {
    float4 v = ((const float4*)Wl)[i];
    store4bf(Wlb + i * 4, v);
  }
  for (long i = tid0; i < 1024L * 1024 / 4; i += stride) {
    float4 v = ((const float4*)Wd)[i];
    store4bf(Wdb + i * 4, v);
  }
  for (long i = tid0; i < B_ROWS; i += stride) {
    float dt = inp[i * 1025 + 1024];
    Tm1[i] = 1.0f / logf(dt + 2.7183f) - 1.0f;
  }
}

// ---------- kernel 1: C_ST GEMM (8192x1024x1024) + h_adj epilogue (known-good) ----------
__global__ void k_gemm1(const unsigned short* __restrict__ A,   // hb  [8192][1024]
                        const unsigned short* __restrict__ Bm,  // Wdb [1024][1024]
                        const float* __restrict__ h,            // h_cur f32
                        const float* __restrict__ bd,           // b_desc [1024]
                        const float* __restrict__ Tm1,
                        unsigned short* __restrict__ comb) {
  const int K = 1024;
  __shared__ __align__(16) unsigned short As[128 * 32];
  __shared__ __align__(16) unsigned short Bs[128 * 32];
  const int tid = threadIdx.x;
  const int lane = tid & 63;
  const int wave = tid >> 6;
  const int wr = wave >> 1, wc = wave & 1;
  const int bRow = blockIdx.x;    // 0..63
  const int bCol = blockIdx.y;    // 0..7

  const int sRow = tid >> 2;
  const int sK = (tid & 3) * 8;
  const unsigned short* aSrc0 = A + (long)(bRow * 128 + sRow) * K + sK;
  const unsigned short* aSrc1 = A + (long)(bRow * 128 + 64 + sRow) * K + sK;
  const unsigned short* bSrc0 = Bm + (long)(bCol * 128 + sRow) * K + sK;
  const unsigned short* bSrc1 = Bm + (long)(bCol * 128 + 64 + sRow) * K + sK;
  unsigned short* aDst0 = As + tid * 8;
  unsigned short* aDst1 = As + 2048 + tid * 8;
  unsigned short* bDst0 = Bs + tid * 8;
  unsigned short* bDst1 = Bs + 2048 + tid * 8;

  f32x4 acc[4][4] = {};
  const int fr = lane & 15, fk = (lane >> 4) * 8;

  for (int k0 = 0; k0 < K; k0 += 32) {
    GLOAD16(aSrc0 + k0, aDst0);
    GLOAD16(aSrc1 + k0, aDst1);
    GLOAD16(bSrc0 + k0, bDst0);
    GLOAD16(bSrc1 + k0, bDst1);
    __syncthreads();
    bf16x8 a[4], b[4];
#pragma unroll
    for (int m = 0; m < 4; m++) a[m] = *(const bf16x8*)(As + (wr * 64 + m * 16 + fr) * 32 + fk);
#pragma unroll
    for (int n = 0; n < 4; n++) b[n] = *(const bf16x8*)(Bs + (wc * 64 + n * 16 + fr) * 32 + fk);
#pragma unroll
    for (int m = 0; m < 4; m++)
#pragma unroll
      for (int n = 0; n < 4; n++)
        acc[m][n] = __builtin_amdgcn_mfma_f32_16x16x32_bf16(a[m], b[n], acc[m][n], 0, 0, 0);
    __syncthreads();
  }

  const int cr = (lane >> 4) * 4;
  const int cc = lane & 15;
#pragma unroll
  for (int m = 0; m < 4; m++)
#pragma unroll
    for (int n = 0; n < 4; n++) {
      const int col = bCol * 128 + wc * 64 + n * 16 + cc;
#pragma unroll
      for (int r = 0; r < 4; r++) {
        const int row = bRow * 128 + wr * 64 + m * 16 + cr + r;
        float v = acc[m][n][r] + bd[col];
        float cst = tanhf(v);
        float hadj = h[(long)row * HSZ + col] + Tm1[row] * cst;
        comb[(long)row * 2048 + 1024 + col] = f2bf(hadj);
      }
    }
}

// ---------- kernel 2: gates GEMM, 256x256, ring-4 BK=32, TEMPLATE-PHASE schedule ----------
// R10: exact m201 phase discipline, ZERO sched_barrier(0):
//   phase = { ds_reads; stage; s_barrier; bare lgkmcnt(0); setprio1; 16 MFMA; setprio0; s_barrier }
// One "memory"-fenced counted vmcnt(8) per tile (end of p1). Ledger: at that point
// outstanding = {A,B(t+3), A,B(t+2)} = 8 instrs -> tile t+1 proven resident, never drains.
// Tail: vmcnt(4) at t=NT2-3, vmcnt(0) at t=NT2-2. Ring slot (t+3)&3 = slot of t-1, whose
// reads are lgkm-complete before t-1's final barrier < stage issue -> race-free.
#define NT2 64   // 2048/32
__global__ __launch_bounds__(512, 2)
void k_gemm2_tp(const unsigned short* __restrict__ A,   // comb [8192][2048]
                const unsigned short* __restrict__ Bm,  // Wlb  [4096][2048]
                const float* __restrict__ bl,           // b_layers [4096]
                const float* __restrict__ c_cur,        // f32 [8192][1024]
                float* __restrict__ out) {              // h_next | c_next (f32)
  __shared__ __align__(16) unsigned short lds[4][16384];

  const int tid = threadIdx.x;
  const int lane = tid & 63;
  const int wid = tid >> 6;
  const int wr = wid >> 2;          // 0..1 : row half (128 rows)
  const int wc = wid & 3;           // 0..3 : col quarter (16 j x 4 gates)

  // L2-aware XCD mapping (R6, best measured FETCH)
  const int bid = blockIdx.x;
  const int xcd = bid & 7;
  const int ii = bid >> 3;
  const int sweep = ii >> 5;
  const int pos = ii & 31;
  const int bRow = xcd * 4 + sweep * 2 + (pos & 1);   // 0..31
  const int bCol = pos >> 1;                          // 0..15

  // ---- staging addresses (pre-swizzled global source; LDS dest linear) ----
  const int sr = tid >> 2;                 // 0..127
  const int swsel = (sr >> 1) & 3;
  const int gk = ((tid & 3) ^ swsel) << 3;
  const unsigned short* aBase = A + (long)(bRow * 256 + sr) * 2048 + gk;
  const int rl0 = sr, rl1 = 128 + sr;
  const int grow0 = ((rl0 >> 4) & 3) * 1024 + bCol * 64 + (rl0 >> 6) * 16 + (rl0 & 15);
  const int grow1 = ((rl1 >> 4) & 3) * 1024 + bCol * 64 + (rl1 >> 6) * 16 + (rl1 & 15);
  const unsigned short* bBase0 = Bm + (long)grow0 * 2048 + gk;
  const unsigned short* bBase1 = Bm + (long)grow1 * 2048 + gk;

#define STAGE_A2(tt) { unsigned short* d_ = &lds[(tt) & 3][0] + tid * 8;          \
    GLOAD16(aBase + (long)(tt) * 32, d_);                                          \
    GLOAD16(aBase + 128L * 2048 + (long)(tt) * 32, d_ + 512 * 8); }
#define STAGE_B2(tt) { unsigned short* d_ = &lds[(tt) & 3][8192] + tid * 8;       \
    GLOAD16(bBase0 + (long)(tt) * 32, d_);                                         \
    GLOAD16(bBase1 + (long)(tt) * 32, d_ + 512 * 8); }

  // ---- fragment read offsets (swizzled), in ushort units ----
  const int fr = lane & 15, q = lane >> 4;
  int offA[8], offB[4];
#pragma unroll
  for (int m = 0; m < 8; m++) {
    const int row = wr * 128 + m * 16 + fr;
    offA[m] = row * 32 + ((q ^ ((row >> 1) & 3)) << 3);
  }
#pragma unroll
  for (int n = 0; n < 4; n++) {
    const int row = wc * 64 + n * 16 + fr;
    offB[n] = 8192 + row * 32 + ((q ^ ((row >> 1) & 3)) << 3);
  }

  f32x4 acc[8][4] = {};   // [m][gate]

  // ---- prologue: stage tiles 0,1,2; publish tile 0 ----
  STAGE_A2(0); STAGE_B2(0);
  STAGE_A2(1); STAGE_B2(1);
  STAGE_A2(2); STAGE_B2(2);
  asm volatile("s_waitcnt vmcnt(8)" ::: "memory");   // oldest 4 = tile 0 A+B landed
  __builtin_amdgcn_s_barrier();

  for (int t = 0; t < NT2; ++t) {
    const unsigned short* buf = lds[t & 3];
    bf16x8 aL[4], aH[4], bF[4];
    // ---- phase 0: reads (A m0-3, B all) ; stage A(t+3) ; barrier ; lgkm0 ; MFMA ----
#pragma unroll
    for (int m = 0; m < 4; m++) aL[m] = *(const bf16x8*)(buf + offA[m]);
#pragma unroll
    for (int n = 0; n < 4; n++) bF[n] = *(const bf16x8*)(buf + offB[n]);
    if (t < NT2 - 3) STAGE_A2(t + 3);
    __builtin_amdgcn_s_barrier();
    asm volatile("s_waitcnt lgkmcnt(0)");
    __builtin_amdgcn_s_setprio(1);
#pragma unroll
    for (int m = 0; m < 4; m++)
#pragma unroll
      for (int n = 0; n < 4; n++)
        acc[m][n] = __builtin_amdgcn_mfma_f32_16x16x32_bf16(aL[m], bF[n], acc[m][n], 0, 0, 0);
    __builtin_amdgcn_s_setprio(0);
    __builtin_amdgcn_s_barrier();
    // ---- phase 1: reads (A m4-7) ; stage B(t+3) ; barrier ; lgkm0 ; MFMA ; vmcnt ----
#pragma unroll
    for (int m = 0; m < 4; m++) aH[m] = *(const bf16x8*)(buf + offA[m + 4]);
    if (t < NT2 - 3) STAGE_B2(t + 3);
    __builtin_amdgcn_s_barrier();
    asm volatile("s_waitcnt lgkmcnt(0)");
    __builtin_amdgcn_s_setprio(1);
#pragma unroll
    for (int m = 0; m < 4; m++)
#pragma unroll
      for (int n = 0; n < 4; n++)
        acc[m + 4][n] = __builtin_amdgcn_mfma_f32_16x16x32_bf16(aH[m], bF[n], acc[m + 4][n], 0, 0, 0);
    __builtin_amdgcn_s_setprio(0);
    if (t < NT2 - 3)       { asm volatile("s_waitcnt vmcnt(8)" ::: "memory"); }
    else if (t == NT2 - 3) { asm volatile("s_waitcnt vmcnt(4)" ::: "memory"); }
    else if (t == NT2 - 2) { asm volatile("s_waitcnt vmcnt(0)" ::: "memory"); }
    __builtin_amdgcn_s_barrier();
  }

  // ---- fused LSTM epilogue ----
  const int cr = (lane >> 4) * 4;
  const int cc = lane & 15;
  const int j = bCol * 64 + wc * 16 + cc;       // 0..1023
#pragma unroll
  for (int m = 0; m < 8; m++) {
#pragma unroll
    for (int r = 0; r < 4; r++) {
      const int row = bRow * 256 + wr * 128 + m * 16 + cr + r;
      float iv = sigm(acc[m][0][r] + bl[j]);
      float fv = sigm(acc[m][1][r] + bl[1024 + j]);
      float ov = sigm(acc[m][2][r] + bl[2048 + j]);
      float gv = tanhf(acc[m][3][r] + bl[3072 + j]);
      float cn = fv * c_cur[(long)row * HSZ + j] + iv * gv;
      float hn = ov * tanhf(cn);
      out[(long)row * HSZ + j] = hn;                         // h_next
      out[(long)B_ROWS * HSZ + (long)row * HSZ + j] = cn;    // c_next
    }
  }
}

// ---------- launch ----------
extern "C" void kernel_launch(void* const* d_in, const int* in_sizes, int n_in,
                              void* d_out, int out_size, void* d_ws, size_t ws_size,
                              hipStream_t stream) {
  const float* inp = (const float*)d_in[0];   // input_tensor [8192][1025]
  const float* h   = (const float*)d_in[1];   // h_cur
  const float* c   = (const float*)d_in[2];   // c_cur
  const float* Wl  = (const float*)d_in[3];   // W_layers [4096][2048]
  const float* bl  = (const float*)d_in[4];   // b_layers [4096]
  const float* Wd  = (const float*)d_in[5];   // W_desc [1024][1024]
  const float* bd  = (const float*)d_in[6];   // b_desc [1024]

  char* ws = (char*)d_ws;
  unsigned short* comb = (unsigned short*)(ws);               // 33,554,432 B
  unsigned short* Wlb  = (unsigned short*)(ws + 33554432);    // 16,777,216 B
  unsigned short* hb   = (unsigned short*)(ws + 50331648);    // 16,777,216 B
  unsigned short* Wdb  = (unsigned short*)(ws + 67108864);    //  2,097,152 B
  float*          Tm1  = (float*)(ws + 69206016);             //     32,768 B
  float*          out  = (float*)d_out;                       // f32 outputs

  hipLaunchKernelGGL(k_convert, dim3(2048), dim3(256), 0, stream,
                     inp, h, Wl, Wd, comb, Wlb, hb, Wdb, Tm1);
  hipLaunchKernelGGL(k_gemm1, dim3(64, 8), dim3(256), 0, stream,
                     hb, Wdb, h, bd, Tm1, comb);
  hipLaunchKernelGGL(k_gemm2_tp, dim3(512), dim3(512), 0, stream,
                     comb, Wlb, bl, c, out);
}

// Round 11
// 226.211 us; speedup vs baseline: 1.2827x; 1.0518x over previous
//
#include <hip/hip_runtime.h>
#include <hip/hip_bf16.h>
#include <math.h>

// ---------- types ----------
typedef __bf16 bf16x8 __attribute__((ext_vector_type(8)));
typedef float  f32x4  __attribute__((ext_vector_type(4)));

#define B_ROWS 8192
#define HSZ    1024

// async global->LDS, 16B per lane. LDS dest must be wave-uniform-base + lane*16.
#define GLOAD16(gsrc, ldst)                                                          \
  __builtin_amdgcn_global_load_lds((const __attribute__((address_space(1))) void*)(gsrc), \
                                   (__attribute__((address_space(3))) void*)(ldst),  \
                                   16, 0, 0)

__device__ inline unsigned short f2bf(float f) {
  union { float f; unsigned u; } x; x.f = f;
  unsigned r = x.u + 0x7fffu + ((x.u >> 16) & 1u);   // RNE
  return (unsigned short)(r >> 16);
}

__device__ inline void store4bf(unsigned short* p, float4 v) {
  ushort4 u;
  u.x = f2bf(v.x); u.y = f2bf(v.y); u.z = f2bf(v.z); u.w = f2bf(v.w);
  *(ushort4*)p = u;  // 8B store
}

__device__ inline float sigm(float x) { return 1.0f / (1.0f + __expf(-x)); }

// ---------- kernel 0: fp32 -> bf16 conversion + T precompute ----------
__global__ void k_convert(const float* __restrict__ inp,   // [8192][1025]
                          const float* __restrict__ h,     // [8192][1024]
                          const float* __restrict__ Wl,    // [4096][2048]
                          const float* __restrict__ Wd,    // [1024][1024]
                          unsigned short* __restrict__ comb, // [8192][2048] bf16 bits (cols 0..1023 = x)
                          unsigned short* __restrict__ Wlb,  // [4096][2048]
                          unsigned short* __restrict__ hb,   // [8192][1024]
                          unsigned short* __restrict__ Wdb,  // [1024][1024]
                          float* __restrict__ Tm1) {         // [8192] = T-1
  const long stride = (long)gridDim.x * blockDim.x;
  const long tid0 = (long)blockIdx.x * blockDim.x + threadIdx.x;

  for (long i = tid0; i < (long)B_ROWS * HSZ / 4; i += stride) {
    float4 v = ((const float4*)h)[i];
    store4bf(hb + i * 4, v);
  }
  for (long i = tid0; i < (long)B_ROWS * HSZ / 4; i += stride) {
    long e = i * 4; long b = e >> 10; long c = e & 1023;
    float4 v = *(const float4*)(inp + b * 1025 + c);
    store4bf(comb + b * 2048 + c, v);
  }
  for (long i = tid0; i < 4096L * 2048 / 4; i += stride) {
    float4 v = ((const float4*)Wl)[i];
    store4bf(Wlb + i * 4, v);
  }
  for (long i = tid0; i < 1024L * 1024 / 4; i += stride) {
    float4 v = ((const float4*)Wd)[i];
    store4bf(Wdb + i * 4, v);
  }
  for (long i = tid0; i < B_ROWS; i += stride) {
    float dt = inp[i * 1025 + 1024];
    Tm1[i] = 1.0f / logf(dt + 2.7183f) - 1.0f;
  }
}

// ---------- kernel 1: C_ST GEMM (8192x1024x1024) + h_adj epilogue (known-good) ----------
__global__ void k_gemm1(const unsigned short* __restrict__ A,   // hb  [8192][1024]
                        const unsigned short* __restrict__ Bm,  // Wdb [1024][1024]
                        const float* __restrict__ h,            // h_cur f32
                        const float* __restrict__ bd,           // b_desc [1024]
                        const float* __restrict__ Tm1,
                        unsigned short* __restrict__ comb) {
  const int K = 1024;
  __shared__ __align__(16) unsigned short As[128 * 32];
  __shared__ __align__(16) unsigned short Bs[128 * 32];
  const int tid = threadIdx.x;
  const int lane = tid & 63;
  const int wave = tid >> 6;
  const int wr = wave >> 1, wc = wave & 1;
  const int bRow = blockIdx.x;    // 0..63
  const int bCol = blockIdx.y;    // 0..7

  const int sRow = tid >> 2;
  const int sK = (tid & 3) * 8;
  const unsigned short* aSrc0 = A + (long)(bRow * 128 + sRow) * K + sK;
  const unsigned short* aSrc1 = A + (long)(bRow * 128 + 64 + sRow) * K + sK;
  const unsigned short* bSrc0 = Bm + (long)(bCol * 128 + sRow) * K + sK;
  const unsigned short* bSrc1 = Bm + (long)(bCol * 128 + 64 + sRow) * K + sK;
  unsigned short* aDst0 = As + tid * 8;
  unsigned short* aDst1 = As + 2048 + tid * 8;
  unsigned short* bDst0 = Bs + tid * 8;
  unsigned short* bDst1 = Bs + 2048 + tid * 8;

  f32x4 acc[4][4] = {};
  const int fr = lane & 15, fk = (lane >> 4) * 8;

  for (int k0 = 0; k0 < K; k0 += 32) {
    GLOAD16(aSrc0 + k0, aDst0);
    GLOAD16(aSrc1 + k0, aDst1);
    GLOAD16(bSrc0 + k0, bDst0);
    GLOAD16(bSrc1 + k0, bDst1);
    __syncthreads();
    bf16x8 a[4], b[4];
#pragma unroll
    for (int m = 0; m < 4; m++) a[m] = *(const bf16x8*)(As + (wr * 64 + m * 16 + fr) * 32 + fk);
#pragma unroll
    for (int n = 0; n < 4; n++) b[n] = *(const bf16x8*)(Bs + (wc * 64 + n * 16 + fr) * 32 + fk);
#pragma unroll
    for (int m = 0; m < 4; m++)
#pragma unroll
      for (int n = 0; n < 4; n++)
        acc[m][n] = __builtin_amdgcn_mfma_f32_16x16x32_bf16(a[m], b[n], acc[m][n], 0, 0, 0);
    __syncthreads();
  }

  const int cr = (lane >> 4) * 4;
  const int cc = lane & 15;
#pragma unroll
  for (int m = 0; m < 4; m++)
#pragma unroll
    for (int n = 0; n < 4; n++) {
      const int col = bCol * 128 + wc * 64 + n * 16 + cc;
#pragma unroll
      for (int r = 0; r < 4; r++) {
        const int row = bRow * 128 + wr * 64 + m * 16 + cr + r;
        float v = acc[m][n][r] + bd[col];
        float cst = tanhf(v);
        float hadj = h[(long)row * HSZ + col] + Tm1[row] * cst;
        comb[(long)row * 2048 + 1024 + col] = f2bf(hadj);
      }
    }
}

// ---------- kernel 2: gates GEMM, 256x256, ring-4, FREE-RUNNING minimal-sync tiles ----------
// R11: ONE fence point per K-tile: counted vmcnt ("memory") + one s_barrier. Then
// {stage t+3; 12 ds_reads; 32 MFMA} in a single open scheduling region — no lgkm fences,
// no mid barriers, no sched_barrier(0). Compiler interleaves reads/MFMA with fine-grained
// lgkmcnt (m97-verified codegen); waves drift freely inside the tile window.
// Ledger (4 loads/tile/thread): at tile-t head outstanding = {t,t+1,t+2} = 12
//   -> vmcnt(8) forces stage(t) complete, never drains. Tail: vmcnt(8)@61, (4)@62, (0)@63.
// Ring: stage(t+3) -> slot (t-1)&3; all t-1 reads consumed (reg-dependency) before
// their waves reached tile t's barrier -> race-free.
#define NT2 64   // 2048/32
__global__ __launch_bounds__(512, 2)
void k_gemm2_fr(const unsigned short* __restrict__ A,   // comb [8192][2048]
                const unsigned short* __restrict__ Bm,  // Wlb  [4096][2048]
                const float* __restrict__ bl,           // b_layers [4096]
                const float* __restrict__ c_cur,        // f32 [8192][1024]
                float* __restrict__ out) {              // h_next | c_next (f32)
  __shared__ __align__(16) unsigned short lds[4][16384];

  const int tid = threadIdx.x;
  const int lane = tid & 63;
  const int wid = tid >> 6;
  const int wr = wid >> 2;          // 0..1 : row half (128 rows)
  const int wc = wid & 3;           // 0..3 : col quarter (16 j x 4 gates)

  // L2-aware XCD mapping (R6, best measured FETCH)
  const int bid = blockIdx.x;
  const int xcd = bid & 7;
  const int ii = bid >> 3;
  const int sweep = ii >> 5;
  const int pos = ii & 31;
  const int bRow = xcd * 4 + sweep * 2 + (pos & 1);   // 0..31
  const int bCol = pos >> 1;                          // 0..15

  // ---- staging addresses (pre-swizzled global source; LDS dest linear) ----
  const int sr = tid >> 2;                 // 0..127
  const int swsel = (sr >> 1) & 3;
  const int gk = ((tid & 3) ^ swsel) << 3;
  const unsigned short* aBase = A + (long)(bRow * 256 + sr) * 2048 + gk;
  const int rl0 = sr, rl1 = 128 + sr;
  const int grow0 = ((rl0 >> 4) & 3) * 1024 + bCol * 64 + (rl0 >> 6) * 16 + (rl0 & 15);
  const int grow1 = ((rl1 >> 4) & 3) * 1024 + bCol * 64 + (rl1 >> 6) * 16 + (rl1 & 15);
  const unsigned short* bBase0 = Bm + (long)grow0 * 2048 + gk;
  const unsigned short* bBase1 = Bm + (long)grow1 * 2048 + gk;

#define STAGE_A2(slot, tt) { unsigned short* d_ = &lds[slot][0] + tid * 8;        \
    GLOAD16(aBase + (long)(tt) * 32, d_);                                          \
    GLOAD16(aBase + 128L * 2048 + (long)(tt) * 32, d_ + 512 * 8); }
#define STAGE_B2(slot, tt) { unsigned short* d_ = &lds[slot][8192] + tid * 8;     \
    GLOAD16(bBase0 + (long)(tt) * 32, d_);                                         \
    GLOAD16(bBase1 + (long)(tt) * 32, d_ + 512 * 8); }

  // ---- fragment read offsets (swizzled), in ushort units ----
  const int fr = lane & 15, q = lane >> 4;
  int offA[8], offB[4];
#pragma unroll
  for (int m = 0; m < 8; m++) {
    const int row = wr * 128 + m * 16 + fr;
    offA[m] = row * 32 + ((q ^ ((row >> 1) & 3)) << 3);
  }
#pragma unroll
  for (int n = 0; n < 4; n++) {
    const int row = wc * 64 + n * 16 + fr;
    offB[n] = 8192 + row * 32 + ((q ^ ((row >> 1) & 3)) << 3);
  }

  f32x4 acc[8][4] = {};   // [m][gate]

  // ---- prologue: stage tiles 0,1,2 into slots 0,1,2 ----
  STAGE_A2(0, 0); STAGE_B2(0, 0);
  STAGE_A2(1, 1); STAGE_B2(1, 1);
  STAGE_A2(2, 2); STAGE_B2(2, 2);

  // BODY(t, SLOT, VM, DOSTAGE): one fence point, then a single open region.
#define BODY(t, SLOT, VM, DOSTAGE)                                                   \
  {                                                                                  \
    asm volatile("s_waitcnt vmcnt(" #VM ")" ::: "memory");                           \
    __builtin_amdgcn_s_barrier();                                                    \
    if (DOSTAGE) { STAGE_A2(((t) + 3) & 3, (t) + 3); STAGE_B2(((t) + 3) & 3, (t) + 3); } \
    const unsigned short* buf = &lds[SLOT][0];                                       \
    bf16x8 aF[8], bF[4];                                                             \
    _Pragma("unroll")                                                                \
    for (int n = 0; n < 4; n++) bF[n] = *(const bf16x8*)(buf + offB[n]);             \
    _Pragma("unroll")                                                                \
    for (int m = 0; m < 8; m++) aF[m] = *(const bf16x8*)(buf + offA[m]);             \
    __builtin_amdgcn_s_setprio(1);                                                   \
    _Pragma("unroll")                                                                \
    for (int m = 0; m < 8; m++)                                                      \
      _Pragma("unroll")                                                              \
      for (int n = 0; n < 4; n++)                                                    \
        acc[m][n] = __builtin_amdgcn_mfma_f32_16x16x32_bf16(aF[m], bF[n], acc[m][n], 0, 0, 0); \
    __builtin_amdgcn_s_setprio(0);                                                   \
  }

  // main: t = 0..59 (vmcnt(8), always stage)
  for (int t = 0; t < 60; t += 4) {
    BODY(t,     0, 8, true);
    BODY(t + 1, 1, 8, true);
    BODY(t + 2, 2, 8, true);
    BODY(t + 3, 3, 8, true);
  }
  // tail: 60 stages 63; 61-63 no stage; vmcnt peel 8,8,4,0
  BODY(60, 0, 8, true);
  BODY(61, 1, 8, false);
  BODY(62, 2, 4, false);
  BODY(63, 3, 0, false);
#undef BODY

  // ---- fused LSTM epilogue ----
  const int cr = (lane >> 4) * 4;
  const int cc = lane & 15;
  const int j = bCol * 64 + wc * 16 + cc;       // 0..1023
#pragma unroll
  for (int m = 0; m < 8; m++) {
#pragma unroll
    for (int r = 0; r < 4; r++) {
      const int row = bRow * 256 + wr * 128 + m * 16 + cr + r;
      float iv = sigm(acc[m][0][r] + bl[j]);
      float fv = sigm(acc[m][1][r] + bl[1024 + j]);
      float ov = sigm(acc[m][2][r] + bl[2048 + j]);
      float gv = tanhf(acc[m][3][r] + bl[3072 + j]);
      float cn = fv * c_cur[(long)row * HSZ + j] + iv * gv;
      float hn = ov * tanhf(cn);
      out[(long)row * HSZ + j] = hn;                         // h_next
      out[(long)B_ROWS * HSZ + (long)row * HSZ + j] = cn;    // c_next
    }
  }
}

// ---------- launch ----------
extern "C" void kernel_launch(void* const* d_in, const int* in_sizes, int n_in,
                              void* d_out, int out_size, void* d_ws, size_t ws_size,
                              hipStream_t stream) {
  const float* inp = (const float*)d_in[0];   // input_tensor [8192][1025]
  const float* h   = (const float*)d_in[1];   // h_cur
  const float* c   = (const float*)d_in[2];   // c_cur
  const float* Wl  = (const float*)d_in[3];   // W_layers [4096][2048]
  const float* bl  = (const float*)d_in[4];   // b_layers [4096]
  const float* Wd  = (const float*)d_in[5];   // W_desc [1024][1024]
  const float* bd  = (const float*)d_in[6];   // b_desc [1024]

  char* ws = (char*)d_ws;
  unsigned short* comb = (unsigned short*)(ws);               // 33,554,432 B
  unsigned short* Wlb  = (unsigned short*)(ws + 33554432);    // 16,777,216 B
  unsigned short* hb   = (unsigned short*)(ws + 50331648);    // 16,777,216 B
  unsigned short* Wdb  = (unsigned short*)(ws + 67108864);    //  2,097,152 B
  float*          Tm1  = (float*)(ws + 69206016);             //     32,768 B
  float*          out  = (float*)d_out;                       // f32 outputs

  hipLaunchKernelGGL(k_convert, dim3(2048), dim3(256), 0, stream,
                     inp, h, Wl, Wd, comb, Wlb, hb, Wdb, Tm1);
  hipLaunchKernelGGL(k_gemm1, dim3(64, 8), dim3(256), 0, stream,
                     hb, Wdb, h, bd, Tm1, comb);
  hipLaunchKernelGGL(k_gemm2_fr, dim3(512), dim3(512), 0, stream,
                     comb, Wlb, bl, c, out);
}